// Round 1
// baseline (298.028 us; speedup 1.0000x reference)
//
#include <hip/hip_runtime.h>

typedef _Float16 h2 __attribute__((ext_vector_type(2)));
typedef _Float16 h4 __attribute__((ext_vector_type(4)));
typedef _Float16 h8 __attribute__((ext_vector_type(8)));
typedef float    f4 __attribute__((ext_vector_type(4)));

#define MFMA32(a,b,c) __builtin_amdgcn_mfma_f32_16x16x32_f16((a),(b),(c),0,0,0)
#define MFMA16(a,b,c) __builtin_amdgcn_mfma_f32_16x16x16f16((a),(b),(c),0,0,0)

#define B_N 8
#define C_N 384
#define P_N 4096
#define PI_F 3.14159265358979323846f

__device__ __forceinline__ h4 to_h4(f4 v) {
  h4 r; r[0]=(_Float16)v[0]; r[1]=(_Float16)v[1]; r[2]=(_Float16)v[2]; r[3]=(_Float16)v[3];
  return r;
}

// ---------- setup: fp32->fp16 weights + DCT matrices (Wm and Wm^T) ----------
__global__ __launch_bounds__(256) void k_setup(
    const float* __restrict__ lin_w, const float* __restrict__ tok_w,
    const float* __restrict__ out_w, _Float16* __restrict__ lwh,
    _Float16* __restrict__ twh, _Float16* __restrict__ owh,
    _Float16* __restrict__ wmg, _Float16* __restrict__ wmtg) {
  int t = blockIdx.x * 256 + threadIdx.x;
  if (t < 768*384) lwh[t] = (_Float16)lin_w[t];
  if (t < 384*384) { twh[t] = (_Float16)tok_w[t]; owh[t] = (_Float16)out_w[t]; }
  if (t < 4096) {
    int n = t >> 6, h = t & 63;
    float v = cosf((float)n * ((float)h + 0.5f) * (PI_F / 64.0f)) * 0.1767766952966369f;
    if (n == 0) v *= 0.7071067811865476f;
    wmg[n*64 + h]  = (_Float16)v;
    wmtg[h*64 + n] = (_Float16)v;
  }
}

// ---------- depthwise 3x3 conv (SAME, zero pad) -> xdw[b][p][c] fp16 ----------
__global__ __launch_bounds__(256) void k_dwconv(
    const float* __restrict__ x, const float* __restrict__ dww,
    const float* __restrict__ dwb, _Float16* __restrict__ xdw) {
  int b = blockIdx.x >> 6, h = blockIdx.x & 63;
  int t = threadIdx.x;
  int w = t & 63, ci = t >> 6;         // lane == w within each wave
  __shared__ _Float16 buf[64 * 388];   // [w][c], stride 388 (8B-aligned rows, ~2-way banks)
  const float* xb = x + (size_t)b * C_N * P_N;
  int wl = (w > 0)  ? w - 1 : 0;
  int wr = (w < 63) ? w + 1 : 63;
  for (int c = ci; c < C_N; c += 4) {
    const float* xc = xb + (size_t)c * P_N;
    float k0=dww[c*9+0],k1=dww[c*9+1],k2=dww[c*9+2];
    float k3=dww[c*9+3],k4=dww[c*9+4],k5=dww[c*9+5];
    float k6=dww[c*9+6],k7=dww[c*9+7],k8=dww[c*9+8];
    float top = (h > 0)  ? xc[(h-1)*64 + w] : 0.0f;
    float mid = xc[h*64 + w];
    float bot = (h < 63) ? xc[(h+1)*64 + w] : 0.0f;
    float tl = __shfl(top, wl, 64), tr = __shfl(top, wr, 64);
    float ml = __shfl(mid, wl, 64), mr = __shfl(mid, wr, 64);
    float bl = __shfl(bot, wl, 64), br = __shfl(bot, wr, 64);
    if (w == 0)  { tl = 0.f; ml = 0.f; bl = 0.f; }
    if (w == 63) { tr = 0.f; mr = 0.f; br = 0.f; }
    float acc = dwb[c];
    acc += k0*tl + k1*top + k2*tr;
    acc += k3*ml + k4*mid + k5*mr;
    acc += k6*bl + k7*bot + k8*br;
    buf[w*388 + c] = (_Float16)acc;
  }
  __syncthreads();
  _Float16* op = xdw + ((size_t)b*P_N + h*64) * C_N;  // [p][c], c contiguous
  #pragma unroll
  for (int i = 0; i < 24; i++) {
    int flat = (t + 256*i) * 4;         // 64*384 elems, 4 per store
    int pix = flat / 384, c = flat - pix*384;
    *(h4*)&op[flat] = *(const h4*)&buf[pix*388 + c];
  }
}

// ---------- tok GEMM + trig gate: g[c][p] = cos(c0*t) + (1+a/2)/c0*sin(c0*t) ----------
__global__ __launch_bounds__(256) void k_gate(
    const float* __restrict__ fe, const _Float16* __restrict__ twh,
    const float* __restrict__ tkb, const float* __restrict__ cc,
    const float* __restrict__ aa, _Float16* __restrict__ g) {
  int pt = blockIdx.x & 63, dt = blockIdx.x >> 6;
  int p0 = pt*64, d0 = dt*64;
  int t = threadIdx.x, lane = t & 63, wave = t >> 6;
  int quad = lane >> 4, l15 = lane & 15;
  int wm_ = wave >> 1, wn = wave & 1;
  __shared__ _Float16 la[64*40], lb[64*40];
  int srow = t >> 2, scg = (t & 3) * 8;
  f4 acc[2][2] = {};
  for (int kc = 0; kc < 384; kc += 32) {
    const float* src = fe + (size_t)(p0 + srow)*384 + kc + scg;
    f4 v0 = *(const f4*)src;
    f4 v1 = *(const f4*)(src + 4);
    h8 hv;
    hv[0]=(_Float16)v0[0]; hv[1]=(_Float16)v0[1]; hv[2]=(_Float16)v0[2]; hv[3]=(_Float16)v0[3];
    hv[4]=(_Float16)v1[0]; hv[5]=(_Float16)v1[1]; hv[6]=(_Float16)v1[2]; hv[7]=(_Float16)v1[3];
    *(h8*)&la[srow*40 + scg] = hv;
    *(h8*)&lb[srow*40 + scg] = *(const h8*)&twh[(size_t)(d0 + srow)*384 + kc + scg];
    __syncthreads();
    h8 a0 = *(const h8*)&la[(wm_*32 + l15)*40 + quad*8];
    h8 a1 = *(const h8*)&la[(wm_*32 + 16 + l15)*40 + quad*8];
    h8 b0 = *(const h8*)&lb[(wn*32 + l15)*40 + quad*8];
    h8 b1 = *(const h8*)&lb[(wn*32 + 16 + l15)*40 + quad*8];
    acc[0][0] = MFMA32(a0, b0, acc[0][0]);
    acc[0][1] = MFMA32(a0, b1, acc[0][1]);
    acc[1][0] = MFMA32(a1, b0, acc[1][0]);
    acc[1][1] = MFMA32(a1, b1, acc[1][1]);
    __syncthreads();
  }
  float c0 = cc[0];
  float s1 = (1.0f + 0.5f*aa[0]) / c0;
  #pragma unroll
  for (int i = 0; i < 2; i++)
  #pragma unroll
  for (int j = 0; j < 2; j++) {
    int d  = d0 + wn*32 + j*16 + l15;
    int pl = wm_*32 + i*16 + quad*4;
    float bias = tkb[d];
    h4 hv;
    #pragma unroll
    for (int r = 0; r < 4; r++) {
      float tv = fmaxf(acc[i][j][r] + bias, 0.0f);
      hv[r] = (_Float16)(__cosf(c0*tv) + s1*__sinf(c0*tv));
    }
    *(h4*)&g[(size_t)d*P_N + p0 + pl] = hv;
  }
}

// ---------- GEMM1: xz = xdw @ lin_w^T + b; xs half -> [b][c][p], z half -> silu -> [b][c][p] ----------
__global__ __launch_bounds__(256) void k_gemm1(
    const _Float16* __restrict__ xdw, const _Float16* __restrict__ lwh,
    const float* __restrict__ lnb, _Float16* __restrict__ xs,
    _Float16* __restrict__ zs) {
  int pt = blockIdx.x & 63;
  int rest = blockIdx.x >> 6;
  int dt = rest % 12, b = rest / 12;
  int p0 = pt*64, d0 = dt*64;
  int t = threadIdx.x, lane = t & 63, wave = t >> 6;
  int quad = lane >> 4, l15 = lane & 15;
  int wm_ = wave >> 1, wn = wave & 1;
  __shared__ _Float16 la[64*40], lb[64*40];
  int srow = t >> 2, scg = (t & 3) * 8;
  f4 acc[2][2] = {};
  for (int kc = 0; kc < 384; kc += 32) {
    *(h8*)&la[srow*40 + scg] = *(const h8*)&xdw[((size_t)b*P_N + p0 + srow)*384 + kc + scg];
    *(h8*)&lb[srow*40 + scg] = *(const h8*)&lwh[(size_t)(d0 + srow)*384 + kc + scg];
    __syncthreads();
    h8 a0 = *(const h8*)&la[(wm_*32 + l15)*40 + quad*8];
    h8 a1 = *(const h8*)&la[(wm_*32 + 16 + l15)*40 + quad*8];
    h8 b0 = *(const h8*)&lb[(wn*32 + l15)*40 + quad*8];
    h8 b1 = *(const h8*)&lb[(wn*32 + 16 + l15)*40 + quad*8];
    acc[0][0] = MFMA32(a0, b0, acc[0][0]);
    acc[0][1] = MFMA32(a0, b1, acc[0][1]);
    acc[1][0] = MFMA32(a1, b0, acc[1][0]);
    acc[1][1] = MFMA32(a1, b1, acc[1][1]);
    __syncthreads();
  }
  #pragma unroll
  for (int i = 0; i < 2; i++)
  #pragma unroll
  for (int j = 0; j < 2; j++) {
    int d  = d0 + wn*32 + j*16 + l15;
    int pl = wm_*32 + i*16 + quad*4;
    float bias = lnb[d];
    h4 hv;
    if (d < 384) {
      #pragma unroll
      for (int r = 0; r < 4; r++) hv[r] = (_Float16)(acc[i][j][r] + bias);
      *(h4*)&xs[((size_t)b*C_N + d)*P_N + p0 + pl] = hv;
    } else {
      #pragma unroll
      for (int r = 0; r < 4; r++) {
        float v = acc[i][j][r] + bias;
        v = v / (1.0f + __expf(-v));           // silu fused here
        hv[r] = (_Float16)v;
      }
      *(h4*)&zs[((size_t)b*C_N + (d-384))*P_N + p0 + pl] = hv;
    }
  }
}

// ---------- fused DCT -> gate -> IDCT per (b,c) plane, all-register chain ----------
// Fragment-layout identity used (16x16, k-per-lane = (l>>4)*4+j for K=16):
//   D-layout tile fed as B  => contracts its ROW index (W @ P)
//   D-layout tile fed as A  => acts as P^T, also contracting its ROW index
__global__ __launch_bounds__(256) void k_dct(
    const _Float16* __restrict__ xs, const _Float16* __restrict__ g,
    const _Float16* __restrict__ wmg, const _Float16* __restrict__ wmtg,
    _Float16* __restrict__ xi) {
  int b = blockIdx.x / 96, cg = blockIdx.x % 96;
  int c0 = cg * 4;
  int t = threadIdx.x, wave = t >> 6, lane = t & 63;
  int quad = lane >> 4, l15 = lane & 15;
  __shared__ _Float16 wm_s[64*72];
  __shared__ _Float16 wmt_s[64*72];
  __shared__ _Float16 pb[4][64*72];    // per-wave plane buffer [h][w] (stride 72)
  for (int i = t; i < 512; i += 256) {
    int row = i >> 3, col = (i & 7) * 8;
    *(h8*)&wm_s[row*72 + col]  = *(const h8*)&wmg[row*64 + col];
    *(h8*)&wmt_s[row*72 + col] = *(const h8*)&wmtg[row*64 + col];
  }
  const _Float16* xsb = xs + ((size_t)b*C_N + c0) * P_N;
  for (int i = t; i < 2048; i += 256) {
    int pl = i >> 9, idx = i & 511;
    int p = idx * 8, hh = p >> 6, ww = p & 63;
    *(h8*)&pb[pl][hh*72 + ww] = *(const h8*)&xsb[(size_t)pl*P_N + p];
  }
  __syncthreads();
  // step1: T1[h][k] = S @ Wm^T  (contract w, K=32 MFMA)
  h8 aS[4][2], bW[4][2];
  #pragma unroll
  for (int I = 0; I < 4; I++)
  #pragma unroll
  for (int kk = 0; kk < 2; kk++) {
    aS[I][kk] = *(const h8*)&pb[wave][(I*16 + l15)*72 + kk*32 + quad*8];
    bW[I][kk] = *(const h8*)&wm_s[(I*16 + l15)*72 + kk*32 + quad*8];
  }
  h4 t1h[4][4];
  #pragma unroll
  for (int I = 0; I < 4; I++)
  #pragma unroll
  for (int J = 0; J < 4; J++) {
    f4 a = {};
    a = MFMA32(aS[I][0], bW[J][0], a);
    a = MFMA32(aS[I][1], bW[J][1], a);
    t1h[I][J] = to_h4(a);
  }
  __syncthreads();
  // restage gate plane into pb (S is dead; T1 lives in registers)
  const _Float16* gb = g + (size_t)c0 * P_N;
  for (int i = t; i < 2048; i += 256) {
    int pl = i >> 9, idx = i & 511;
    int p = idx * 8, hh = p >> 6, ww = p & 63;
    *(h8*)&pb[pl][hh*72 + ww] = *(const h8*)&gb[(size_t)pl*P_N + p];
  }
  __syncthreads();
  // step2: Xd[n][k] = Wm @ T1 (T1 as B, contracting its rows h)
  f4 t2[4][4] = {};
  #pragma unroll
  for (int I = 0; I < 4; I++)
  #pragma unroll
  for (int K4 = 0; K4 < 4; K4++) {
    h4 af = *(const h4*)&wm_s[(I*16 + l15)*72 + K4*16 + quad*4];
    #pragma unroll
    for (int J = 0; J < 4; J++) t2[I][J] = MFMA16(af, t1h[K4][J], t2[I][J]);
  }
  // step3: gate F = g .* Xd   (lane's element at [n=quad*4+r+16I][k=l15+16J])
  h4 fh[4][4];
  #pragma unroll
  for (int I = 0; I < 4; I++)
  #pragma unroll
  for (int J = 0; J < 4; J++) {
    int n0 = I*16 + quad*4, k = J*16 + l15;
    h4 r;
    #pragma unroll
    for (int rr = 0; rr < 4; rr++) {
      float gv = (float)pb[wave][(n0+rr)*72 + k];
      r[rr] = (_Float16)(t2[I][J][rr] * gv);
    }
    fh[I][J] = r;
  }
  // step4: X3T[k][h] = F^T @ Wm (F as A => F^T, contracting F's rows n)
  f4 t3[4][4] = {};
  #pragma unroll
  for (int J = 0; J < 4; J++)
  #pragma unroll
  for (int K4 = 0; K4 < 4; K4++) {
    h4 bf = *(const h4*)&wmt_s[(J*16 + l15)*72 + K4*16 + quad*4];
    #pragma unroll
    for (int I = 0; I < 4; I++) t3[I][J] = MFMA16(fh[K4][I], bf, t3[I][J]);
  }
  h4 t3h[4][4];
  #pragma unroll
  for (int I = 0; I < 4; I++)
  #pragma unroll
  for (int J = 0; J < 4; J++) t3h[I][J] = to_h4(t3[I][J]);
  // step5: xiT[w][h] = Wm^T-cols @ X3T (X3T as B, contracting its rows k)
  f4 t4[4][4] = {};
  #pragma unroll
  for (int I = 0; I < 4; I++)
  #pragma unroll
  for (int K4 = 0; K4 < 4; K4++) {
    h4 af = *(const h4*)&wmt_s[(I*16 + l15)*72 + K4*16 + quad*4];
    #pragma unroll
    for (int J = 0; J < 4; J++) t4[I][J] = MFMA16(af, t3h[K4][J], t4[I][J]);
  }
  // write xi^T tiles into own plane buffer as [h][w] (4 consecutive w per lane -> b64)
  #pragma unroll
  for (int I = 0; I < 4; I++)
  #pragma unroll
  for (int J = 0; J < 4; J++) {
    int w0 = I*16 + quad*4, hq = J*16 + l15;
    *(h4*)&pb[wave][hq*72 + w0] = to_h4(t4[I][J]);
  }
  __syncthreads();
  _Float16* xib = xi + ((size_t)b*C_N + c0) * P_N;
  for (int i = t; i < 2048; i += 256) {
    int pl = i >> 9, idx = i & 511;
    int p = idx * 8, hh = p >> 6, ww = p & 63;
    *(h8*)&xib[(size_t)pl*P_N + p] = *(const h8*)&pb[pl][hh*72 + ww];
  }
}

// ---------- LayerNorm stats per pixel ----------
__global__ __launch_bounds__(256) void k_stats(
    const _Float16* __restrict__ xi, float* __restrict__ mu, float* __restrict__ rs) {
  int t = threadIdx.x;
  int pl = t & 63, seg = t >> 6;
  int gp = blockIdx.x * 64 + pl;
  int b = gp >> 12, p = gp & 4095;
  const _Float16* base = xi + (size_t)b * C_N * P_N + p;
  float s = 0.f, ss = 0.f;
  for (int c = seg*96; c < seg*96 + 96; c++) {
    float v = (float)base[(size_t)c * P_N];
    s += v; ss += v*v;
  }
  __shared__ float sb[2][4][64];
  sb[0][seg][pl] = s; sb[1][seg][pl] = ss;
  __syncthreads();
  if (seg == 0) {
    float st  = sb[0][0][pl]+sb[0][1][pl]+sb[0][2][pl]+sb[0][3][pl];
    float sst = sb[1][0][pl]+sb[1][1][pl]+sb[1][2][pl]+sb[1][3][pl];
    float m = st * (1.f/384.f);
    float var = sst * (1.f/384.f) - m*m;
    mu[gp] = m;
    rs[gp] = rsqrtf(var + 1e-5f);
  }
}

// ---------- GEMM2: out[b][d][p] = ow @ (LN(xi)*silu_z) + out_b (fp32 out) ----------
__global__ __launch_bounds__(256) void k_gemm2(
    const _Float16* __restrict__ xi, const _Float16* __restrict__ zs,
    const _Float16* __restrict__ owh, const float* __restrict__ mu,
    const float* __restrict__ rs, const float* __restrict__ lng,
    const float* __restrict__ lnbv, const float* __restrict__ ob,
    float* __restrict__ out) {
  int pt = blockIdx.x & 63;
  int rest = blockIdx.x >> 6;
  int dt = rest % 6, b = rest / 6;
  int p0 = pt*64, d0 = dt*64;
  int t = threadIdx.x, lane = t & 63, wave = t >> 6;
  int quad = lane >> 4, l15 = lane & 15;
  int wm_ = wave >> 1, wn = wave & 1;
  __shared__ _Float16 lb[64*40];
  __shared__ _Float16 lu[64*36];   // u-tile [p][c] as packed c-pairs, row stride 36 f16
  int pg = t & 15, cp = t >> 4;
  int pth = p0 + pg*4;
  f4 muv = *(const f4*)&mu[(size_t)b*P_N + pth];
  f4 rsv = *(const f4*)&rs[(size_t)b*P_N + pth];
  int srow = t >> 2, scg = (t & 3) * 8;
  f4 acc[2][2] = {};
  for (int kc = 0; kc < 384; kc += 32) {
    *(h8*)&lb[srow*40 + scg] = *(const h8*)&owh[(size_t)(d0 + srow)*384 + kc + scg];
    int c = kc + 2*cp;
    const _Float16* xp = &xi[((size_t)b*C_N + c)*P_N + pth];
    const _Float16* zp = &zs[((size_t)b*C_N + c)*P_N + pth];
    h4 x0 = *(const h4*)xp;
    h4 x1 = *(const h4*)(xp + P_N);
    h4 z0 = *(const h4*)zp;
    h4 z1 = *(const h4*)(zp + P_N);
    float g0 = lng[c], g1 = lng[c+1], bb0 = lnbv[c], bb1 = lnbv[c+1];
    #pragma unroll
    for (int q = 0; q < 4; q++) {
      float y0 = ((float)x0[q] - muv[q]) * rsv[q] * g0 + bb0;
      float y1 = ((float)x1[q] - muv[q]) * rsv[q] * g1 + bb1;
      h2 pr;
      pr[0] = (_Float16)(y0 * (float)z0[q]);   // zs already holds silu(z)
      pr[1] = (_Float16)(y1 * (float)z1[q]);
      *(h2*)&lu[(pg*4 + q)*36 + 2*cp] = pr;
    }
    __syncthreads();
    int m0 = wm_*32 + l15, m1 = m0 + 16;
    h4 alo0 = *(const h4*)&lu[m0*36 + quad*8];
    h4 ahi0 = *(const h4*)&lu[m0*36 + quad*8 + 4];
    h4 alo1 = *(const h4*)&lu[m1*36 + quad*8];
    h4 ahi1 = *(const h4*)&lu[m1*36 + quad*8 + 4];
    h8 a0, a1;
    #pragma unroll
    for (int e = 0; e < 4; e++) {
      a0[e]=alo0[e]; a0[e+4]=ahi0[e];
      a1[e]=alo1[e]; a1[e+4]=ahi1[e];
    }
    h8 b0 = *(const h8*)&lb[(wn*32 + l15)*40 + quad*8];
    h8 b1 = *(const h8*)&lb[(wn*32 + 16 + l15)*40 + quad*8];
    acc[0][0] = MFMA32(a0, b0, acc[0][0]);
    acc[0][1] = MFMA32(a0, b1, acc[0][1]);
    acc[1][0] = MFMA32(a1, b0, acc[1][0]);
    acc[1][1] = MFMA32(a1, b1, acc[1][1]);
    __syncthreads();
  }
  #pragma unroll
  for (int i = 0; i < 2; i++)
  #pragma unroll
  for (int j = 0; j < 2; j++) {
    int d  = d0 + wn*32 + j*16 + l15;
    int pl = wm_*32 + i*16 + quad*4;
    float bias = ob[d];
    f4 v;
    #pragma unroll
    for (int r = 0; r < 4; r++) v[r] = acc[i][j][r] + bias;
    *(f4*)&out[((size_t)b*C_N + d)*P_N + p0 + pl] = v;
  }
}

extern "C" void kernel_launch(void* const* d_in, const int* in_sizes, int n_in,
                              void* d_out, int out_size, void* d_ws, size_t ws_size,
                              hipStream_t stream) {
  (void)in_sizes; (void)n_in; (void)out_size; (void)ws_size;
  const float* x    = (const float*)d_in[0];
  const float* fe   = (const float*)d_in[1];
  const float* dww  = (const float*)d_in[2];
  const float* dwb  = (const float*)d_in[3];
  const float* linw = (const float*)d_in[4];
  const float* linb = (const float*)d_in[5];
  const float* tokw = (const float*)d_in[6];
  const float* tokb = (const float*)d_in[7];
  const float* cc   = (const float*)d_in[8];
  const float* aa   = (const float*)d_in[9];
  const float* lng  = (const float*)d_in[10];
  const float* lnbv = (const float*)d_in[11];
  const float* outw = (const float*)d_in[12];
  const float* outb = (const float*)d_in[13];
  float* out = (float*)d_out;

  char* ws = (char*)d_ws;
  size_t off = 0;
  auto alloc = [&](size_t bytes) -> void* {
    void* p = ws + off;
    off += (bytes + 255) & ~(size_t)255;
    return p;
  };
  _Float16* lwh  = (_Float16*)alloc((size_t)768*384*2);
  _Float16* twh  = (_Float16*)alloc((size_t)384*384*2);
  _Float16* owh  = (_Float16*)alloc((size_t)384*384*2);
  _Float16* wmg  = (_Float16*)alloc((size_t)64*64*2);
  _Float16* wmtg = (_Float16*)alloc((size_t)64*64*2);
  _Float16* xdw  = (_Float16*)alloc((size_t)B_N*P_N*C_N*2);
  _Float16* xs   = (_Float16*)alloc((size_t)B_N*C_N*P_N*2);
  _Float16* zs   = (_Float16*)alloc((size_t)B_N*C_N*P_N*2);
  _Float16* gg   = (_Float16*)alloc((size_t)C_N*P_N*2);
  float*    mu   = (float*)alloc((size_t)B_N*P_N*4);
  float*    rsd  = (float*)alloc((size_t)B_N*P_N*4);
  _Float16* xi   = xdw;   // reuse: xdw is dead after k_gemm1; stream order serializes

  k_setup<<<1152, 256, 0, stream>>>(linw, tokw, outw, lwh, twh, owh, wmg, wmtg);
  k_dwconv<<<512, 256, 0, stream>>>(x, dww, dwb, xdw);
  k_gate<<<384, 256, 0, stream>>>(fe, twh, tokb, cc, aa, gg);
  k_gemm1<<<6144, 256, 0, stream>>>(xdw, lwh, linb, xs, zs);
  k_dct<<<768, 256, 0, stream>>>(xs, gg, wmg, wmtg, xi);
  k_stats<<<512, 256, 0, stream>>>(xi, mu, rsd);
  k_gemm2<<<3072, 256, 0, stream>>>(xi, zs, owh, mu, rsd, lng, lnbv, outb, out);
}

// Round 2
// 273.970 us; speedup vs baseline: 1.0878x; 1.0878x over previous
//
#include <hip/hip_runtime.h>

typedef _Float16 h2 __attribute__((ext_vector_type(2)));
typedef _Float16 h4 __attribute__((ext_vector_type(4)));
typedef _Float16 h8 __attribute__((ext_vector_type(8)));
typedef float    f4 __attribute__((ext_vector_type(4)));

#define MFMA32(a,b,c) __builtin_amdgcn_mfma_f32_16x16x32_f16((a),(b),(c),0,0,0)
#define MFMA16(a,b,c) __builtin_amdgcn_mfma_f32_16x16x16f16((a),(b),(c),0,0,0)

#define B_N 8
#define C_N 384
#define P_N 4096
#define PI_F 3.14159265358979323846f

__device__ __forceinline__ h4 to_h4(f4 v) {
  h4 r; r[0]=(_Float16)v[0]; r[1]=(_Float16)v[1]; r[2]=(_Float16)v[2]; r[3]=(_Float16)v[3];
  return r;
}

// async global->LDS, 16B per lane; LDS dest = wave-uniform base + lane*16 (m97/m104)
__device__ __forceinline__ void gl_lds16(const _Float16* g, _Float16* l) {
  __builtin_amdgcn_global_load_lds(
      (const __attribute__((address_space(1))) void*)g,
      (__attribute__((address_space(3))) void*)l, 16, 0, 0);
}

// ---------- setup: fp32->fp16 weights + DCT matrices ----------
__global__ __launch_bounds__(256) void k_setup(
    const float* __restrict__ lin_w, const float* __restrict__ tok_w,
    const float* __restrict__ out_w, _Float16* __restrict__ lwh,
    _Float16* __restrict__ twh, _Float16* __restrict__ owh,
    _Float16* __restrict__ wmg, _Float16* __restrict__ wmtg) {
  int t = blockIdx.x * 256 + threadIdx.x;
  if (t < 768*384) lwh[t] = (_Float16)lin_w[t];
  if (t < 384*384) { twh[t] = (_Float16)tok_w[t]; owh[t] = (_Float16)out_w[t]; }
  if (t < 4096) {
    int n = t >> 6, h = t & 63;
    float v = cosf((float)n * ((float)h + 0.5f) * (PI_F / 64.0f)) * 0.1767766952966369f;
    if (n == 0) v *= 0.7071067811865476f;
    wmg[n*64 + h]  = (_Float16)v;
    wmtg[h*64 + n] = (_Float16)v;
  }
}

// ---------- depthwise 3x3 conv -> xdw[b][p][c] fp16 ----------
// grid: b(8) x cchunk(6) x h(64) = 3072 blocks; 64 c per block -> 12 blk/CU
__global__ __launch_bounds__(256) void k_dwconv(
    const float* __restrict__ x, const float* __restrict__ dww,
    const float* __restrict__ dwb, _Float16* __restrict__ xdw) {
  int blk = blockIdx.x;
  int h = blk & 63;
  int rest = blk >> 6;
  int cgi = rest % 6;
  int b = rest / 6;
  int c0 = cgi * 64;
  int t = threadIdx.x;
  int w = t & 63, ci = t >> 6;        // ci wave-uniform -> weights via s_load
  __shared__ _Float16 buf[64 * 68];   // [w][c_local], stride 68 (2-way banks = free)
  const float* xb = x + (size_t)b * C_N * P_N;
  int wl = (w > 0)  ? w - 1 : 0;
  int wr = (w < 63) ? w + 1 : 63;
  #pragma unroll
  for (int j = 0; j < 8; j++) {
    int lc = ci * 16 + j * 2;
    h2 pr;
    #pragma unroll
    for (int e = 0; e < 2; e++) {
      int c = c0 + lc + e;
      const float* xc = xb + (size_t)c * P_N;
      float k0=dww[c*9+0],k1=dww[c*9+1],k2=dww[c*9+2];
      float k3=dww[c*9+3],k4=dww[c*9+4],k5=dww[c*9+5];
      float k6=dww[c*9+6],k7=dww[c*9+7],k8=dww[c*9+8];
      float top = (h > 0)  ? xc[(h-1)*64 + w] : 0.0f;
      float mid = xc[h*64 + w];
      float bot = (h < 63) ? xc[(h+1)*64 + w] : 0.0f;
      float tl = __shfl(top, wl, 64), tr = __shfl(top, wr, 64);
      float ml = __shfl(mid, wl, 64), mr = __shfl(mid, wr, 64);
      float bl = __shfl(bot, wl, 64), br = __shfl(bot, wr, 64);
      if (w == 0)  { tl = 0.f; ml = 0.f; bl = 0.f; }
      if (w == 63) { tr = 0.f; mr = 0.f; br = 0.f; }
      float acc = dwb[c];
      acc += k0*tl + k1*top + k2*tr;
      acc += k3*ml + k4*mid + k5*mr;
      acc += k6*bl + k7*bot + k8*br;
      pr[e] = (_Float16)acc;
    }
    *(h2*)&buf[w*68 + lc] = pr;
  }
  __syncthreads();
  _Float16* op = xdw + ((size_t)b*P_N + h*64) * C_N + c0;
  #pragma unroll
  for (int i = 0; i < 4; i++) {
    int flat = (t + 256*i) * 4;        // 64px * 64c
    int pix = flat >> 6, cl = flat & 63;
    *(h4*)&op[(size_t)pix*C_N + cl] = *(const h4*)&buf[pix*68 + cl];
  }
}

// ---------- tok GEMM + trig gate ----------
__global__ __launch_bounds__(256) void k_gate(
    const float* __restrict__ fe, const _Float16* __restrict__ twh,
    const float* __restrict__ tkb, const float* __restrict__ cc,
    const float* __restrict__ aa, _Float16* __restrict__ g) {
  int pt = blockIdx.x & 63, dt = blockIdx.x >> 6;
  int p0 = pt*64, d0 = dt*64;
  int t = threadIdx.x, lane = t & 63, wave = t >> 6;
  int quad = lane >> 4, l15 = lane & 15;
  int wm_ = wave >> 1, wn = wave & 1;
  __shared__ _Float16 la[64*40], lb[64*40];
  int srow = t >> 2, scg = (t & 3) * 8;
  f4 acc[2][2] = {};
  for (int kc = 0; kc < 384; kc += 32) {
    const float* src = fe + (size_t)(p0 + srow)*384 + kc + scg;
    f4 v0 = *(const f4*)src;
    f4 v1 = *(const f4*)(src + 4);
    h8 hv;
    hv[0]=(_Float16)v0[0]; hv[1]=(_Float16)v0[1]; hv[2]=(_Float16)v0[2]; hv[3]=(_Float16)v0[3];
    hv[4]=(_Float16)v1[0]; hv[5]=(_Float16)v1[1]; hv[6]=(_Float16)v1[2]; hv[7]=(_Float16)v1[3];
    *(h8*)&la[srow*40 + scg] = hv;
    *(h8*)&lb[srow*40 + scg] = *(const h8*)&twh[(size_t)(d0 + srow)*384 + kc + scg];
    __syncthreads();
    h8 a0 = *(const h8*)&la[(wm_*32 + l15)*40 + quad*8];
    h8 a1 = *(const h8*)&la[(wm_*32 + 16 + l15)*40 + quad*8];
    h8 b0 = *(const h8*)&lb[(wn*32 + l15)*40 + quad*8];
    h8 b1 = *(const h8*)&lb[(wn*32 + 16 + l15)*40 + quad*8];
    acc[0][0] = MFMA32(a0, b0, acc[0][0]);
    acc[0][1] = MFMA32(a0, b1, acc[0][1]);
    acc[1][0] = MFMA32(a1, b0, acc[1][0]);
    acc[1][1] = MFMA32(a1, b1, acc[1][1]);
    __syncthreads();
  }
  float c0 = cc[0];
  float s1 = (1.0f + 0.5f*aa[0]) / c0;
  #pragma unroll
  for (int i = 0; i < 2; i++)
  #pragma unroll
  for (int j = 0; j < 2; j++) {
    int d  = d0 + wn*32 + j*16 + l15;
    int pl = wm_*32 + i*16 + quad*4;
    float bias = tkb[d];
    h4 hv;
    #pragma unroll
    for (int r = 0; r < 4; r++) {
      float tv = fmaxf(acc[i][j][r] + bias, 0.0f);
      hv[r] = (_Float16)(__cosf(c0*tv) + s1*__sinf(c0*tv));
    }
    *(h4*)&g[(size_t)d*P_N + p0 + pl] = hv;
  }
}

// ---------- GEMM1: 128x128 tile, global_load_lds staging (m97 structure) ----------
__global__ __launch_bounds__(256) void k_gemm1(
    const _Float16* __restrict__ xdw, const _Float16* __restrict__ lwh,
    const float* __restrict__ lnb, _Float16* __restrict__ xs,
    _Float16* __restrict__ zs) {
  int pt = blockIdx.x & 31;
  int rest = blockIdx.x >> 5;
  int dt = rest % 6, b = rest / 6;
  int p0 = pt * 128, d0 = dt * 128;
  int t = threadIdx.x, lane = t & 63, wave = t >> 6;
  int quad = lane >> 4, l15 = lane & 15;
  int wm = wave >> 1, wn = wave & 1;
  __shared__ _Float16 la[128 * 32];   // unpadded: required by global_load_lds
  __shared__ _Float16 lb[128 * 32];
  int s_row = lane >> 2;
  int s_col = (lane & 3) * 8;
  const _Float16* ga = xdw + ((size_t)b*P_N + p0) * 384 + s_col;
  const _Float16* gb = lwh + (size_t)d0 * 384 + s_col;
  f4 acc[4][4] = {};
  for (int kc = 0; kc < 384; kc += 32) {
    #pragma unroll
    for (int s = 0; s < 2; s++) {
      int seg = wave * 2 + s;
      int row = seg * 16 + s_row;
      gl_lds16(ga + (size_t)row*384 + kc, &la[seg*512 + lane*8]);
      gl_lds16(gb + (size_t)row*384 + kc, &lb[seg*512 + lane*8]);
    }
    __syncthreads();
    h8 af[4], bf[4];
    #pragma unroll
    for (int i = 0; i < 4; i++) {
      af[i] = *(const h8*)&la[(wm*64 + i*16 + l15)*32 + quad*8];
      bf[i] = *(const h8*)&lb[(wn*64 + i*16 + l15)*32 + quad*8];
    }
    #pragma unroll
    for (int i = 0; i < 4; i++)
    #pragma unroll
    for (int j = 0; j < 4; j++)
      acc[i][j] = MFMA32(af[i], bf[j], acc[i][j]);
    __syncthreads();
  }
  bool isz = (d0 >= 384);
  #pragma unroll
  for (int j = 0; j < 4; j++) {
    int d = d0 + wn*64 + j*16 + l15;
    float bias = lnb[d];
    _Float16* dst = isz ? (zs + ((size_t)b*C_N + (d-384)) * P_N)
                        : (xs + ((size_t)b*C_N + d) * P_N);
    #pragma unroll
    for (int i = 0; i < 4; i++) {
      int p = p0 + wm*64 + i*16 + quad*4;
      h4 hv;
      if (isz) {
        #pragma unroll
        for (int r = 0; r < 4; r++) {
          float v = acc[i][j][r] + bias;
          v = v / (1.0f + __expf(-v));     // silu fused
          hv[r] = (_Float16)v;
        }
      } else {
        #pragma unroll
        for (int r = 0; r < 4; r++) hv[r] = (_Float16)(acc[i][j][r] + bias);
      }
      *(h4*)&dst[p] = hv;
    }
  }
}

// ---------- fused DCT -> gate -> IDCT (unchanged, verified) ----------
__global__ __launch_bounds__(256) void k_dct(
    const _Float16* __restrict__ xs, const _Float16* __restrict__ g,
    const _Float16* __restrict__ wmg, const _Float16* __restrict__ wmtg,
    _Float16* __restrict__ xi) {
  int b = blockIdx.x / 96, cg = blockIdx.x % 96;
  int c0 = cg * 4;
  int t = threadIdx.x, wave = t >> 6, lane = t & 63;
  int quad = lane >> 4, l15 = lane & 15;
  __shared__ _Float16 wm_s[64*72];
  __shared__ _Float16 wmt_s[64*72];
  __shared__ _Float16 pb[4][64*72];
  for (int i = t; i < 512; i += 256) {
    int row = i >> 3, col = (i & 7) * 8;
    *(h8*)&wm_s[row*72 + col]  = *(const h8*)&wmg[row*64 + col];
    *(h8*)&wmt_s[row*72 + col] = *(const h8*)&wmtg[row*64 + col];
  }
  const _Float16* xsb = xs + ((size_t)b*C_N + c0) * P_N;
  for (int i = t; i < 2048; i += 256) {
    int pl = i >> 9, idx = i & 511;
    int p = idx * 8, hh = p >> 6, ww = p & 63;
    *(h8*)&pb[pl][hh*72 + ww] = *(const h8*)&xsb[(size_t)pl*P_N + p];
  }
  __syncthreads();
  h8 aS[4][2], bW[4][2];
  #pragma unroll
  for (int I = 0; I < 4; I++)
  #pragma unroll
  for (int kk = 0; kk < 2; kk++) {
    aS[I][kk] = *(const h8*)&pb[wave][(I*16 + l15)*72 + kk*32 + quad*8];
    bW[I][kk] = *(const h8*)&wm_s[(I*16 + l15)*72 + kk*32 + quad*8];
  }
  h4 t1h[4][4];
  #pragma unroll
  for (int I = 0; I < 4; I++)
  #pragma unroll
  for (int J = 0; J < 4; J++) {
    f4 a = {};
    a = MFMA32(aS[I][0], bW[J][0], a);
    a = MFMA32(aS[I][1], bW[J][1], a);
    t1h[I][J] = to_h4(a);
  }
  __syncthreads();
  const _Float16* gb = g + (size_t)c0 * P_N;
  for (int i = t; i < 2048; i += 256) {
    int pl = i >> 9, idx = i & 511;
    int p = idx * 8, hh = p >> 6, ww = p & 63;
    *(h8*)&pb[pl][hh*72 + ww] = *(const h8*)&gb[(size_t)pl*P_N + p];
  }
  __syncthreads();
  f4 t2[4][4] = {};
  #pragma unroll
  for (int I = 0; I < 4; I++)
  #pragma unroll
  for (int K4 = 0; K4 < 4; K4++) {
    h4 af = *(const h4*)&wm_s[(I*16 + l15)*72 + K4*16 + quad*4];
    #pragma unroll
    for (int J = 0; J < 4; J++) t2[I][J] = MFMA16(af, t1h[K4][J], t2[I][J]);
  }
  h4 fh[4][4];
  #pragma unroll
  for (int I = 0; I < 4; I++)
  #pragma unroll
  for (int J = 0; J < 4; J++) {
    int n0 = I*16 + quad*4, k = J*16 + l15;
    h4 r;
    #pragma unroll
    for (int rr = 0; rr < 4; rr++) {
      float gv = (float)pb[wave][(n0+rr)*72 + k];
      r[rr] = (_Float16)(t2[I][J][rr] * gv);
    }
    fh[I][J] = r;
  }
  f4 t3[4][4] = {};
  #pragma unroll
  for (int J = 0; J < 4; J++)
  #pragma unroll
  for (int K4 = 0; K4 < 4; K4++) {
    h4 bf = *(const h4*)&wmt_s[(J*16 + l15)*72 + K4*16 + quad*4];
    #pragma unroll
    for (int I = 0; I < 4; I++) t3[I][J] = MFMA16(fh[K4][I], bf, t3[I][J]);
  }
  h4 t3h[4][4];
  #pragma unroll
  for (int I = 0; I < 4; I++)
  #pragma unroll
  for (int J = 0; J < 4; J++) t3h[I][J] = to_h4(t3[I][J]);
  f4 t4[4][4] = {};
  #pragma unroll
  for (int I = 0; I < 4; I++)
  #pragma unroll
  for (int K4 = 0; K4 < 4; K4++) {
    h4 af = *(const h4*)&wmt_s[(I*16 + l15)*72 + K4*16 + quad*4];
    #pragma unroll
    for (int J = 0; J < 4; J++) t4[I][J] = MFMA16(af, t3h[K4][J], t4[I][J]);
  }
  #pragma unroll
  for (int I = 0; I < 4; I++)
  #pragma unroll
  for (int J = 0; J < 4; J++) {
    int w0 = I*16 + quad*4, hq = J*16 + l15;
    *(h4*)&pb[wave][hq*72 + w0] = to_h4(t4[I][J]);
  }
  __syncthreads();
  _Float16* xib = xi + ((size_t)b*C_N + c0) * P_N;
  for (int i = t; i < 2048; i += 256) {
    int pl = i >> 9, idx = i & 511;
    int p = idx * 8, hh = p >> 6, ww = p & 63;
    *(h8*)&xib[(size_t)pl*P_N + p] = *(const h8*)&pb[pl][hh*72 + ww];
  }
}

// ---------- LayerNorm stats per pixel ----------
__global__ __launch_bounds__(256) void k_stats(
    const _Float16* __restrict__ xi, float* __restrict__ mu, float* __restrict__ rs) {
  int t = threadIdx.x;
  int pl = t & 63, seg = t >> 6;
  int gp = blockIdx.x * 64 + pl;
  int b = gp >> 12, p = gp & 4095;
  const _Float16* base = xi + (size_t)b * C_N * P_N + p;
  float s = 0.f, ss = 0.f;
  for (int c = seg*96; c < seg*96 + 96; c++) {
    float v = (float)base[(size_t)c * P_N];
    s += v; ss += v*v;
  }
  __shared__ float sb[2][4][64];
  sb[0][seg][pl] = s; sb[1][seg][pl] = ss;
  __syncthreads();
  if (seg == 0) {
    float st  = sb[0][0][pl]+sb[0][1][pl]+sb[0][2][pl]+sb[0][3][pl];
    float sst = sb[1][0][pl]+sb[1][1][pl]+sb[1][2][pl]+sb[1][3][pl];
    float m = st * (1.f/384.f);
    float var = sst * (1.f/384.f) - m*m;
    mu[gp] = m;
    rs[gp] = rsqrtf(var + 1e-5f);
  }
}

// ---------- GEMM2: 128x128 tile; A = LN(xi)*silu_z built in registers ----------
__global__ __launch_bounds__(256) void k_gemm2(
    const _Float16* __restrict__ xi, const _Float16* __restrict__ zs,
    const _Float16* __restrict__ owh, const float* __restrict__ mu,
    const float* __restrict__ rs, const float* __restrict__ lng,
    const float* __restrict__ lnbv, const float* __restrict__ ob,
    float* __restrict__ out) {
  int pt = blockIdx.x & 31;
  int rest = blockIdx.x >> 5;
  int dt = rest % 3, b = rest / 3;
  int p0 = pt * 128, d0 = dt * 128;
  int t = threadIdx.x, lane = t & 63, wave = t >> 6;
  int quad = lane >> 4, l15 = lane & 15;
  int wm = wave >> 1, wn = wave & 1;
  __shared__ _Float16 la[128 * 40];   // u-tile [px][c], stride 40
  __shared__ _Float16 lb[128 * 32];   // owh tile, unpadded for global_load_lds
  int s_row = lane >> 2, s_col = (lane & 3) * 8;
  const _Float16* gbp = owh + (size_t)d0 * 384 + s_col;
  int pg = t >> 3;            // 32 px-groups of 4  (bank-spread mapping)
  int cgI = t & 7;            // 8 c-groups of 4
  int pth = p0 + pg * 4;
  f4 muv = *(const f4*)&mu[(size_t)b*P_N + pth];
  f4 rsv = *(const f4*)&rs[(size_t)b*P_N + pth];
  f4 acc[4][4] = {};
  for (int kc = 0; kc < 384; kc += 32) {
    #pragma unroll
    for (int s = 0; s < 2; s++) {
      int seg = wave * 2 + s;
      int row = seg * 16 + s_row;
      gl_lds16(gbp + (size_t)row*384 + kc, &lb[seg*512 + lane*8]);
    }
    int c = kc + cgI * 4;
    f4 gv = *(const f4*)&lng[c];
    f4 bv = *(const f4*)&lnbv[c];
    _Float16 uv[4][4];                 // [px q][c e]
    #pragma unroll
    for (int e = 0; e < 4; e++) {
      const _Float16* xp = &xi[((size_t)b*C_N + c + e) * P_N + pth];
      const _Float16* zp = &zs[((size_t)b*C_N + c + e) * P_N + pth];
      h4 xv = *(const h4*)xp;
      h4 zv = *(const h4*)zp;
      #pragma unroll
      for (int q = 0; q < 4; q++) {
        float y = ((float)xv[q] - muv[q]) * rsv[q] * gv[e] + bv[e];
        uv[q][e] = (_Float16)(y * (float)zv[q]);   // zs holds silu(z)
      }
    }
    #pragma unroll
    for (int q = 0; q < 4; q++) {
      h4 hv; hv[0]=uv[q][0]; hv[1]=uv[q][1]; hv[2]=uv[q][2]; hv[3]=uv[q][3];
      *(h4*)&la[(pg*4 + q)*40 + cgI*4] = hv;
    }
    __syncthreads();
    h8 af[4], bf[4];
    #pragma unroll
    for (int i = 0; i < 4; i++) {
      af[i] = *(const h8*)&la[(wm*64 + i*16 + l15)*40 + quad*8];
      bf[i] = *(const h8*)&lb[(wn*64 + i*16 + l15)*32 + quad*8];
    }
    #pragma unroll
    for (int i = 0; i < 4; i++)
    #pragma unroll
    for (int j = 0; j < 4; j++)
      acc[i][j] = MFMA32(af[i], bf[j], acc[i][j]);
    __syncthreads();
  }
  #pragma unroll
  for (int j = 0; j < 4; j++) {
    int d = d0 + wn*64 + j*16 + l15;
    float bias = ob[d];
    #pragma unroll
    for (int i = 0; i < 4; i++) {
      int p = p0 + wm*64 + i*16 + quad*4;
      f4 v;
      #pragma unroll
      for (int r = 0; r < 4; r++) v[r] = acc[i][j][r] + bias;
      *(f4*)&out[((size_t)b*C_N + d)*P_N + p] = v;
    }
  }
}

extern "C" void kernel_launch(void* const* d_in, const int* in_sizes, int n_in,
                              void* d_out, int out_size, void* d_ws, size_t ws_size,
                              hipStream_t stream) {
  (void)in_sizes; (void)n_in; (void)out_size; (void)ws_size;
  const float* x    = (const float*)d_in[0];
  const float* fe   = (const float*)d_in[1];
  const float* dww  = (const float*)d_in[2];
  const float* dwb  = (const float*)d_in[3];
  const float* linw = (const float*)d_in[4];
  const float* linb = (const float*)d_in[5];
  const float* tokw = (const float*)d_in[6];
  const float* tokb = (const float*)d_in[7];
  const float* cc   = (const float*)d_in[8];
  const float* aa   = (const float*)d_in[9];
  const float* lng  = (const float*)d_in[10];
  const float* lnbv = (const float*)d_in[11];
  const float* outw = (const float*)d_in[12];
  const float* outb = (const float*)d_in[13];
  float* out = (float*)d_out;

  char* ws = (char*)d_ws;
  size_t off = 0;
  auto alloc = [&](size_t bytes) -> void* {
    void* p = ws + off;
    off += (bytes + 255) & ~(size_t)255;
    return p;
  };
  _Float16* lwh  = (_Float16*)alloc((size_t)768*384*2);
  _Float16* twh  = (_Float16*)alloc((size_t)384*384*2);
  _Float16* owh  = (_Float16*)alloc((size_t)384*384*2);
  _Float16* wmg  = (_Float16*)alloc((size_t)64*64*2);
  _Float16* wmtg = (_Float16*)alloc((size_t)64*64*2);
  _Float16* xdw  = (_Float16*)alloc((size_t)B_N*P_N*C_N*2);
  _Float16* xs   = (_Float16*)alloc((size_t)B_N*C_N*P_N*2);
  _Float16* zs   = (_Float16*)alloc((size_t)B_N*C_N*P_N*2);
  _Float16* gg   = (_Float16*)alloc((size_t)C_N*P_N*2);
  float*    mu   = (float*)alloc((size_t)B_N*P_N*4);
  float*    rsd  = (float*)alloc((size_t)B_N*P_N*4);
  _Float16* xi   = xdw;   // xdw dead after k_gemm1; stream order serializes

  k_setup<<<1152, 256, 0, stream>>>(linw, tokw, outw, lwh, twh, owh, wmg, wmtg);
  k_dwconv<<<3072, 256, 0, stream>>>(x, dww, dwb, xdw);
  k_gate<<<384, 256, 0, stream>>>(fe, twh, tokb, cc, aa, gg);
  k_gemm1<<<1536, 256, 0, stream>>>(xdw, lwh, linb, xs, zs);
  k_dct<<<768, 256, 0, stream>>>(xs, gg, wmg, wmtg, xi);
  k_stats<<<512, 256, 0, stream>>>(xi, mu, rsd);
  k_gemm2<<<768, 256, 0, stream>>>(xi, zs, owh, mu, rsd, lng, lnbv, outb, out);
}

// Round 3
// 257.933 us; speedup vs baseline: 1.1554x; 1.0622x over previous
//
#include <hip/hip_runtime.h>

typedef _Float16 h2 __attribute__((ext_vector_type(2)));
typedef _Float16 h4 __attribute__((ext_vector_type(4)));
typedef _Float16 h8 __attribute__((ext_vector_type(8)));
typedef float    f4 __attribute__((ext_vector_type(4)));

#define MFMA32(a,b,c) __builtin_amdgcn_mfma_f32_16x16x32_f16((a),(b),(c),0,0,0)
#define MFMA16(a,b,c) __builtin_amdgcn_mfma_f32_16x16x16f16((a),(b),(c),0,0,0)

#define B_N 8
#define C_N 384
#define P_N 4096
#define PI_F 3.14159265358979323846f

__device__ __forceinline__ h4 to_h4(f4 v) {
  h4 r; r[0]=(_Float16)v[0]; r[1]=(_Float16)v[1]; r[2]=(_Float16)v[2]; r[3]=(_Float16)v[3];
  return r;
}

// async global->LDS, 16B per lane; LDS dest = wave-uniform base + lane*16 (m97/m104)
__device__ __forceinline__ void gl_lds16(const _Float16* g, _Float16* l) {
  __builtin_amdgcn_global_load_lds(
      (const __attribute__((address_space(1))) void*)g,
      (__attribute__((address_space(3))) void*)l, 16, 0, 0);
}

// ---------- setup: fp32->fp16 weights + DCT matrices ----------
__global__ __launch_bounds__(256) void k_setup(
    const float* __restrict__ lin_w, const float* __restrict__ tok_w,
    const float* __restrict__ out_w, _Float16* __restrict__ lwh,
    _Float16* __restrict__ twh, _Float16* __restrict__ owh,
    _Float16* __restrict__ wmg, _Float16* __restrict__ wmtg) {
  int t = blockIdx.x * 256 + threadIdx.x;
  if (t < 768*384) lwh[t] = (_Float16)lin_w[t];
  if (t < 384*384) { twh[t] = (_Float16)tok_w[t]; owh[t] = (_Float16)out_w[t]; }
  if (t < 4096) {
    int n = t >> 6, h = t & 63;
    float v = cosf((float)n * ((float)h + 0.5f) * (PI_F / 64.0f)) * 0.1767766952966369f;
    if (n == 0) v *= 0.7071067811865476f;
    wmg[n*64 + h]  = (_Float16)v;
    wmtg[h*64 + n] = (_Float16)v;
  }
}

// ---------- depthwise 3x3 conv -> xdw[b][p][c] fp16 ----------
__global__ __launch_bounds__(256) void k_dwconv(
    const float* __restrict__ x, const float* __restrict__ dww,
    const float* __restrict__ dwb, _Float16* __restrict__ xdw) {
  int blk = blockIdx.x;
  int h = blk & 63;
  int rest = blk >> 6;
  int cgi = rest % 6;
  int b = rest / 6;
  int c0 = cgi * 64;
  int t = threadIdx.x;
  int w = t & 63, ci = t >> 6;
  __shared__ _Float16 buf[64 * 68];
  const float* xb = x + (size_t)b * C_N * P_N;
  int wl = (w > 0)  ? w - 1 : 0;
  int wr = (w < 63) ? w + 1 : 63;
  #pragma unroll
  for (int j = 0; j < 8; j++) {
    int lc = ci * 16 + j * 2;
    h2 pr;
    #pragma unroll
    for (int e = 0; e < 2; e++) {
      int c = c0 + lc + e;
      const float* xc = xb + (size_t)c * P_N;
      float k0=dww[c*9+0],k1=dww[c*9+1],k2=dww[c*9+2];
      float k3=dww[c*9+3],k4=dww[c*9+4],k5=dww[c*9+5];
      float k6=dww[c*9+6],k7=dww[c*9+7],k8=dww[c*9+8];
      float top = (h > 0)  ? xc[(h-1)*64 + w] : 0.0f;
      float mid = xc[h*64 + w];
      float bot = (h < 63) ? xc[(h+1)*64 + w] : 0.0f;
      float tl = __shfl(top, wl, 64), tr = __shfl(top, wr, 64);
      float ml = __shfl(mid, wl, 64), mr = __shfl(mid, wr, 64);
      float bl = __shfl(bot, wl, 64), br = __shfl(bot, wr, 64);
      if (w == 0)  { tl = 0.f; ml = 0.f; bl = 0.f; }
      if (w == 63) { tr = 0.f; mr = 0.f; br = 0.f; }
      float acc = dwb[c];
      acc += k0*tl + k1*top + k2*tr;
      acc += k3*ml + k4*mid + k5*mr;
      acc += k6*bl + k7*bot + k8*br;
      pr[e] = (_Float16)acc;
    }
    *(h2*)&buf[w*68 + lc] = pr;
  }
  __syncthreads();
  _Float16* op = xdw + ((size_t)b*P_N + h*64) * C_N + c0;
  #pragma unroll
  for (int i = 0; i < 4; i++) {
    int flat = (t + 256*i) * 4;
    int pix = flat >> 6, cl = flat & 63;
    *(h4*)&op[(size_t)pix*C_N + cl] = *(const h4*)&buf[pix*68 + cl];
  }
}

// ---------- tok GEMM + trig gate ----------
__global__ __launch_bounds__(256) void k_gate(
    const float* __restrict__ fe, const _Float16* __restrict__ twh,
    const float* __restrict__ tkb, const float* __restrict__ cc,
    const float* __restrict__ aa, _Float16* __restrict__ g) {
  int pt = blockIdx.x & 63, dt = blockIdx.x >> 6;
  int p0 = pt*64, d0 = dt*64;
  int t = threadIdx.x, lane = t & 63, wave = t >> 6;
  int quad = lane >> 4, l15 = lane & 15;
  int wm_ = wave >> 1, wn = wave & 1;
  __shared__ _Float16 la[64*40], lb[64*40];
  int srow = t >> 2, scg = (t & 3) * 8;
  f4 acc[2][2] = {};
  for (int kc = 0; kc < 384; kc += 32) {
    const float* src = fe + (size_t)(p0 + srow)*384 + kc + scg;
    f4 v0 = *(const f4*)src;
    f4 v1 = *(const f4*)(src + 4);
    h8 hv;
    hv[0]=(_Float16)v0[0]; hv[1]=(_Float16)v0[1]; hv[2]=(_Float16)v0[2]; hv[3]=(_Float16)v0[3];
    hv[4]=(_Float16)v1[0]; hv[5]=(_Float16)v1[1]; hv[6]=(_Float16)v1[2]; hv[7]=(_Float16)v1[3];
    *(h8*)&la[srow*40 + scg] = hv;
    *(h8*)&lb[srow*40 + scg] = *(const h8*)&twh[(size_t)(d0 + srow)*384 + kc + scg];
    __syncthreads();
    h8 a0 = *(const h8*)&la[(wm_*32 + l15)*40 + quad*8];
    h8 a1 = *(const h8*)&la[(wm_*32 + 16 + l15)*40 + quad*8];
    h8 b0 = *(const h8*)&lb[(wn*32 + l15)*40 + quad*8];
    h8 b1 = *(const h8*)&lb[(wn*32 + 16 + l15)*40 + quad*8];
    acc[0][0] = MFMA32(a0, b0, acc[0][0]);
    acc[0][1] = MFMA32(a0, b1, acc[0][1]);
    acc[1][0] = MFMA32(a1, b0, acc[1][0]);
    acc[1][1] = MFMA32(a1, b1, acc[1][1]);
    __syncthreads();
  }
  float c0 = cc[0];
  float s1 = (1.0f + 0.5f*aa[0]) / c0;
  #pragma unroll
  for (int i = 0; i < 2; i++)
  #pragma unroll
  for (int j = 0; j < 2; j++) {
    int d  = d0 + wn*32 + j*16 + l15;
    int pl = wm_*32 + i*16 + quad*4;
    float bias = tkb[d];
    h4 hv;
    #pragma unroll
    for (int r = 0; r < 4; r++) {
      float tv = fmaxf(acc[i][j][r] + bias, 0.0f);
      hv[r] = (_Float16)(__cosf(c0*tv) + s1*__sinf(c0*tv));
    }
    *(h4*)&g[(size_t)d*P_N + p0 + pl] = hv;
  }
}

// ---------- GEMM1: 128x128 tile, global_load_lds staging ----------
__global__ __launch_bounds__(256) void k_gemm1(
    const _Float16* __restrict__ xdw, const _Float16* __restrict__ lwh,
    const float* __restrict__ lnb, _Float16* __restrict__ xs,
    _Float16* __restrict__ zs) {
  int pt = blockIdx.x & 31;
  int rest = blockIdx.x >> 5;
  int dt = rest % 6, b = rest / 6;
  int p0 = pt * 128, d0 = dt * 128;
  int t = threadIdx.x, lane = t & 63, wave = t >> 6;
  int quad = lane >> 4, l15 = lane & 15;
  int wm = wave >> 1, wn = wave & 1;
  __shared__ _Float16 la[128 * 32];
  __shared__ _Float16 lb[128 * 32];
  int s_row = lane >> 2;
  int s_col = (lane & 3) * 8;
  const _Float16* ga = xdw + ((size_t)b*P_N + p0) * 384 + s_col;
  const _Float16* gb = lwh + (size_t)d0 * 384 + s_col;
  f4 acc[4][4] = {};
  for (int kc = 0; kc < 384; kc += 32) {
    #pragma unroll
    for (int s = 0; s < 2; s++) {
      int seg = wave * 2 + s;
      int row = seg * 16 + s_row;
      gl_lds16(ga + (size_t)row*384 + kc, &la[seg*512 + lane*8]);
      gl_lds16(gb + (size_t)row*384 + kc, &lb[seg*512 + lane*8]);
    }
    __syncthreads();
    h8 af[4], bf[4];
    #pragma unroll
    for (int i = 0; i < 4; i++) {
      af[i] = *(const h8*)&la[(wm*64 + i*16 + l15)*32 + quad*8];
      bf[i] = *(const h8*)&lb[(wn*64 + i*16 + l15)*32 + quad*8];
    }
    #pragma unroll
    for (int i = 0; i < 4; i++)
    #pragma unroll
    for (int j = 0; j < 4; j++)
      acc[i][j] = MFMA32(af[i], bf[j], acc[i][j]);
    __syncthreads();
  }
  bool isz = (d0 >= 384);
  #pragma unroll
  for (int j = 0; j < 4; j++) {
    int d = d0 + wn*64 + j*16 + l15;
    float bias = lnb[d];
    _Float16* dst = isz ? (zs + ((size_t)b*C_N + (d-384)) * P_N)
                        : (xs + ((size_t)b*C_N + d) * P_N);
    #pragma unroll
    for (int i = 0; i < 4; i++) {
      int p = p0 + wm*64 + i*16 + quad*4;
      h4 hv;
      if (isz) {
        #pragma unroll
        for (int r = 0; r < 4; r++) {
          float v = acc[i][j][r] + bias;
          v = v / (1.0f + __expf(-v));
          hv[r] = (_Float16)v;
        }
      } else {
        #pragma unroll
        for (int r = 0; r < 4; r++) hv[r] = (_Float16)(acc[i][j][r] + bias);
      }
      *(h4*)&dst[p] = hv;
    }
  }
}

// ---------- fused DCT -> gate -> IDCT ----------
__global__ __launch_bounds__(256) void k_dct(
    const _Float16* __restrict__ xs, const _Float16* __restrict__ g,
    const _Float16* __restrict__ wmg, const _Float16* __restrict__ wmtg,
    _Float16* __restrict__ xi) {
  int b = blockIdx.x / 96, cg = blockIdx.x % 96;
  int c0 = cg * 4;
  int t = threadIdx.x, wave = t >> 6, lane = t & 63;
  int quad = lane >> 4, l15 = lane & 15;
  __shared__ _Float16 wm_s[64*72];
  __shared__ _Float16 wmt_s[64*72];
  __shared__ _Float16 pb[4][64*72];
  for (int i = t; i < 512; i += 256) {
    int row = i >> 3, col = (i & 7) * 8;
    *(h8*)&wm_s[row*72 + col]  = *(const h8*)&wmg[row*64 + col];
    *(h8*)&wmt_s[row*72 + col] = *(const h8*)&wmtg[row*64 + col];
  }
  const _Float16* xsb = xs + ((size_t)b*C_N + c0) * P_N;
  for (int i = t; i < 2048; i += 256) {
    int pl = i >> 9, idx = i & 511;
    int p = idx * 8, hh = p >> 6, ww = p & 63;
    *(h8*)&pb[pl][hh*72 + ww] = *(const h8*)&xsb[(size_t)pl*P_N + p];
  }
  __syncthreads();
  h8 aS[4][2], bW[4][2];
  #pragma unroll
  for (int I = 0; I < 4; I++)
  #pragma unroll
  for (int kk = 0; kk < 2; kk++) {
    aS[I][kk] = *(const h8*)&pb[wave][(I*16 + l15)*72 + kk*32 + quad*8];
    bW[I][kk] = *(const h8*)&wm_s[(I*16 + l15)*72 + kk*32 + quad*8];
  }
  h4 t1h[4][4];
  #pragma unroll
  for (int I = 0; I < 4; I++)
  #pragma unroll
  for (int J = 0; J < 4; J++) {
    f4 a = {};
    a = MFMA32(aS[I][0], bW[J][0], a);
    a = MFMA32(aS[I][1], bW[J][1], a);
    t1h[I][J] = to_h4(a);
  }
  __syncthreads();
  const _Float16* gb = g + (size_t)c0 * P_N;
  for (int i = t; i < 2048; i += 256) {
    int pl = i >> 9, idx = i & 511;
    int p = idx * 8, hh = p >> 6, ww = p & 63;
    *(h8*)&pb[pl][hh*72 + ww] = *(const h8*)&gb[(size_t)pl*P_N + p];
  }
  __syncthreads();
  f4 t2[4][4] = {};
  #pragma unroll
  for (int I = 0; I < 4; I++)
  #pragma unroll
  for (int K4 = 0; K4 < 4; K4++) {
    h4 af = *(const h4*)&wm_s[(I*16 + l15)*72 + K4*16 + quad*4];
    #pragma unroll
    for (int J = 0; J < 4; J++) t2[I][J] = MFMA16(af, t1h[K4][J], t2[I][J]);
  }
  h4 fh[4][4];
  #pragma unroll
  for (int I = 0; I < 4; I++)
  #pragma unroll
  for (int J = 0; J < 4; J++) {
    int n0 = I*16 + quad*4, k = J*16 + l15;
    h4 r;
    #pragma unroll
    for (int rr = 0; rr < 4; rr++) {
      float gv = (float)pb[wave][(n0+rr)*72 + k];
      r[rr] = (_Float16)(t2[I][J][rr] * gv);
    }
    fh[I][J] = r;
  }
  f4 t3[4][4] = {};
  #pragma unroll
  for (int J = 0; J < 4; J++)
  #pragma unroll
  for (int K4 = 0; K4 < 4; K4++) {
    h4 bf = *(const h4*)&wmt_s[(J*16 + l15)*72 + K4*16 + quad*4];
    #pragma unroll
    for (int I = 0; I < 4; I++) t3[I][J] = MFMA16(fh[K4][I], bf, t3[I][J]);
  }
  h4 t3h[4][4];
  #pragma unroll
  for (int I = 0; I < 4; I++)
  #pragma unroll
  for (int J = 0; J < 4; J++) t3h[I][J] = to_h4(t3[I][J]);
  f4 t4[4][4] = {};
  #pragma unroll
  for (int I = 0; I < 4; I++)
  #pragma unroll
  for (int K4 = 0; K4 < 4; K4++) {
    h4 af = *(const h4*)&wmt_s[(I*16 + l15)*72 + K4*16 + quad*4];
    #pragma unroll
    for (int J = 0; J < 4; J++) t4[I][J] = MFMA16(af, t3h[K4][J], t4[I][J]);
  }
  #pragma unroll
  for (int I = 0; I < 4; I++)
  #pragma unroll
  for (int J = 0; J < 4; J++) {
    int w0 = I*16 + quad*4, hq = J*16 + l15;
    *(h4*)&pb[wave][hq*72 + w0] = to_h4(t4[I][J]);
  }
  __syncthreads();
  _Float16* xib = xi + ((size_t)b*C_N + c0) * P_N;
  for (int i = t; i < 2048; i += 256) {
    int pl = i >> 9, idx = i & 511;
    int p = idx * 8, hh = p >> 6, ww = p & 63;
    *(h8*)&xib[(size_t)pl*P_N + p] = *(const h8*)&pb[pl][hh*72 + ww];
  }
}

// ---------- ubuild: stats + LN + *silu(z), [c][p] -> u[p][c] transpose ----------
__global__ __launch_bounds__(256) void k_ubuild(
    const _Float16* __restrict__ xi, const _Float16* __restrict__ zs,
    const float* __restrict__ lng, const float* __restrict__ lnbv,
    _Float16* __restrict__ u) {
  int b = blockIdx.x >> 6, pt = blockIdx.x & 63;
  int p0 = pt * 64;
  int t = threadIdx.x;
  __shared__ _Float16 ut[64 * 392];    // [px][c], 784B rows (16B-aligned)
  __shared__ float red[4][64], red2[4][64];
  __shared__ float muL[64], rsL[64];
  int cr = t >> 3;            // c-row within group of 32
  int px0 = (t & 7) * 8;      // 8 px per lane
  const _Float16* xib = xi + (size_t)b * C_N * P_N;
  #pragma unroll
  for (int i = 0; i < 12; i++) {
    int c = cr + 32 * i;
    h8 v = *(const h8*)&xib[(size_t)c * P_N + p0 + px0];
    #pragma unroll
    for (int e = 0; e < 8; e++) ut[(px0 + e) * 392 + c] = v[e];
  }
  __syncthreads();
  int px = t & 63, seg = t >> 6;
  float s = 0.f, ss = 0.f;
  #pragma unroll
  for (int j = 0; j < 12; j++) {
    h8 v = *(const h8*)&ut[px * 392 + seg * 96 + j * 8];
    #pragma unroll
    for (int e = 0; e < 8; e++) { float f = (float)v[e]; s += f; ss += f * f; }
  }
  red[seg][px] = s; red2[seg][px] = ss;
  __syncthreads();
  if (t < 64) {
    float st  = red[0][t] + red[1][t] + red[2][t] + red[3][t];
    float sst = red2[0][t] + red2[1][t] + red2[2][t] + red2[3][t];
    float m = st * (1.f/384.f);
    float var = sst * (1.f/384.f) - m * m;
    muL[t] = m; rsL[t] = rsqrtf(var + 1e-5f);
  }
  __syncthreads();
  const _Float16* zb = zs + (size_t)b * C_N * P_N;
  #pragma unroll
  for (int i = 0; i < 12; i++) {
    int c = cr + 32 * i;
    float g = lng[c], bb = lnbv[c];
    h8 zv = *(const h8*)&zb[(size_t)c * P_N + p0 + px0];
    #pragma unroll
    for (int e = 0; e < 8; e++) {
      int p = px0 + e;
      float y = ((float)ut[p * 392 + c] - muL[p]) * rsL[p] * g + bb;
      ut[p * 392 + c] = (_Float16)(y * (float)zv[e]);   // zs holds silu(z)
    }
  }
  __syncthreads();
  _Float16* ub = u + ((size_t)b * P_N + p0) * C_N;
  #pragma unroll
  for (int i = 0; i < 12; i++) {
    int idx = t + 256 * i;            // 3072 chunks of 8
    int row = idx / 48, ch = idx % 48;
    *(h8*)&ub[(size_t)row * C_N + ch * 8] = *(const h8*)&ut[row * 392 + ch * 8];
  }
}

// ---------- GEMM2: pure m97-style GEMM  u[p][c] x owh[d][c] -> out fp32 ----------
__global__ __launch_bounds__(256) void k_gemm2(
    const _Float16* __restrict__ u, const _Float16* __restrict__ owh,
    const float* __restrict__ ob, float* __restrict__ out) {
  int pt = blockIdx.x & 31;
  int rest = blockIdx.x >> 5;
  int dt = rest % 3, b = rest / 3;
  int p0 = pt * 128, d0 = dt * 128;
  int t = threadIdx.x, lane = t & 63, wave = t >> 6;
  int quad = lane >> 4, l15 = lane & 15;
  int wm = wave >> 1, wn = wave & 1;
  __shared__ _Float16 la[128 * 32];
  __shared__ _Float16 lb[128 * 32];
  int s_row = lane >> 2;
  int s_col = (lane & 3) * 8;
  const _Float16* ga = u   + ((size_t)b*P_N + p0) * 384 + s_col;
  const _Float16* gb = owh + (size_t)d0 * 384 + s_col;
  f4 acc[4][4] = {};
  for (int kc = 0; kc < 384; kc += 32) {
    #pragma unroll
    for (int s = 0; s < 2; s++) {
      int seg = wave * 2 + s;
      int row = seg * 16 + s_row;
      gl_lds16(ga + (size_t)row*384 + kc, &la[seg*512 + lane*8]);
      gl_lds16(gb + (size_t)row*384 + kc, &lb[seg*512 + lane*8]);
    }
    __syncthreads();
    h8 af[4], bf[4];
    #pragma unroll
    for (int i = 0; i < 4; i++) {
      af[i] = *(const h8*)&la[(wm*64 + i*16 + l15)*32 + quad*8];
      bf[i] = *(const h8*)&lb[(wn*64 + i*16 + l15)*32 + quad*8];
    }
    #pragma unroll
    for (int i = 0; i < 4; i++)
    #pragma unroll
    for (int j = 0; j < 4; j++)
      acc[i][j] = MFMA32(af[i], bf[j], acc[i][j]);
    __syncthreads();
  }
  #pragma unroll
  for (int j = 0; j < 4; j++) {
    int d = d0 + wn*64 + j*16 + l15;
    float bias = ob[d];
    #pragma unroll
    for (int i = 0; i < 4; i++) {
      int p = p0 + wm*64 + i*16 + quad*4;
      f4 v;
      #pragma unroll
      for (int r = 0; r < 4; r++) v[r] = acc[i][j][r] + bias;
      *(f4*)&out[((size_t)b*C_N + d)*P_N + p] = v;
    }
  }
}

extern "C" void kernel_launch(void* const* d_in, const int* in_sizes, int n_in,
                              void* d_out, int out_size, void* d_ws, size_t ws_size,
                              hipStream_t stream) {
  (void)in_sizes; (void)n_in; (void)out_size; (void)ws_size;
  const float* x    = (const float*)d_in[0];
  const float* fe   = (const float*)d_in[1];
  const float* dww  = (const float*)d_in[2];
  const float* dwb  = (const float*)d_in[3];
  const float* linw = (const float*)d_in[4];
  const float* linb = (const float*)d_in[5];
  const float* tokw = (const float*)d_in[6];
  const float* tokb = (const float*)d_in[7];
  const float* cc   = (const float*)d_in[8];
  const float* aa   = (const float*)d_in[9];
  const float* lng  = (const float*)d_in[10];
  const float* lnbv = (const float*)d_in[11];
  const float* outw = (const float*)d_in[12];
  const float* outb = (const float*)d_in[13];
  float* out = (float*)d_out;

  char* ws = (char*)d_ws;
  size_t off = 0;
  auto alloc = [&](size_t bytes) -> void* {
    void* p = ws + off;
    off += (bytes + 255) & ~(size_t)255;
    return p;
  };
  _Float16* lwh  = (_Float16*)alloc((size_t)768*384*2);
  _Float16* twh  = (_Float16*)alloc((size_t)384*384*2);
  _Float16* owh  = (_Float16*)alloc((size_t)384*384*2);
  _Float16* wmg  = (_Float16*)alloc((size_t)64*64*2);
  _Float16* wmtg = (_Float16*)alloc((size_t)64*64*2);
  _Float16* xdw  = (_Float16*)alloc((size_t)B_N*P_N*C_N*2);
  _Float16* xs   = (_Float16*)alloc((size_t)B_N*C_N*P_N*2);
  _Float16* zs   = (_Float16*)alloc((size_t)B_N*C_N*P_N*2);
  _Float16* gg   = (_Float16*)alloc((size_t)C_N*P_N*2);
  _Float16* xi   = xdw;   // xdw dead after k_gemm1
  _Float16* uu   = xs;    // xs dead after k_dct

  k_setup<<<1152, 256, 0, stream>>>(linw, tokw, outw, lwh, twh, owh, wmg, wmtg);
  k_dwconv<<<3072, 256, 0, stream>>>(x, dww, dwb, xdw);
  k_gate<<<384, 256, 0, stream>>>(fe, twh, tokb, cc, aa, gg);
  k_gemm1<<<1536, 256, 0, stream>>>(xdw, lwh, linb, xs, zs);
  k_dct<<<768, 256, 0, stream>>>(xs, gg, wmg, wmtg, xi);
  k_ubuild<<<512, 256, 0, stream>>>(xi, zs, lng, lnbv, uu);
  k_gemm2<<<768, 256, 0, stream>>>(uu, owh, outb, out);
}